// Round 13
// baseline (266.316 us; speedup 1.0000x reference)
//
#include <hip/hip_runtime.h>
#include <hip/hip_bf16.h>
#include <stdint.h>

// Round 13: swapped-operand GEMM1 (h^T in registers) + ds_bpermute in-register
// transpose -> h NEVER touches LDS. LDS = 22KB staging only; regs <=170 via
// 2-pass GEMM2 -> 3 waves/SIMD (12 waves/CU, was 8). Barrier skeleton = r12's
// proven __syncthreads structure. Math bit-identical to r6-r12 (absmax 0.03125).
// Key identity: A-frag and B-frag share the same lane->(k,row/col) map, so
// swapping mfma args transposes the output for free; pack kernel unchanged.

typedef __attribute__((ext_vector_type(8))) short short8;
typedef __attribute__((ext_vector_type(4))) float float4v;

#define MFMA16 __builtin_amdgcn_mfma_f32_16x16x32_bf16

__device__ __align__(16) uint16_t g_wpack[98816];

static __device__ __forceinline__ void gl_lds16(const void* g, void* l) {
    __builtin_amdgcn_global_load_lds(
        (const __attribute__((address_space(1))) unsigned int*)g,
        (__attribute__((address_space(3))) unsigned int*)l, 16, 0, 0);
}

static __device__ __forceinline__ uint16_t f2bf(float f) {
    __hip_bfloat16 h = __float2bfloat16(f);
    return *reinterpret_cast<uint16_t*>(&h);
}

static __device__ __forceinline__ int pk2(float lo, float hi) {
    __hip_bfloat162 b = __float22bfloat162_rn(make_float2(lo, hi));
    int u; __builtin_memcpy(&u, &b, 4); return u;
}

static __device__ __forceinline__ short8 cvt8(float4v x0, float4v x1) {
    union { __hip_bfloat162 b2[4]; short8 s; } u;
    u.b2[0] = __float22bfloat162_rn(make_float2(x0[0], x0[1]));
    u.b2[1] = __float22bfloat162_rn(make_float2(x0[2], x0[3]));
    u.b2[2] = __float22bfloat162_rn(make_float2(x1[0], x1[1]));
    u.b2[3] = __float22bfloat162_rn(make_float2(x1[2], x1[3]));
    return u.s;
}

// ---- weight packing into g_wpack (fragment order; UNCHANGED) ----
// W1p: 9kt x 9nt (K=288 pad, N=144 pad) @u16 0      (41472)
// W2p: 5kt x 16nt (K=160 pad, N=256)    @u16 41472  (40960)
// Wip: 16kt x 2nt (K=512,    N=32 pad)  @u16 82432  (16384)
__global__ __launch_bounds__(256) void pack_weights(
    const float* __restrict__ W1, const float* __restrict__ W2,
    const float* __restrict__ Wi)
{
    int e = blockIdx.x * 256 + threadIdx.x;
    const float* W; int NT, Kr, Nr, ld, le, base;
    if (e < 41472)      { W = W1; NT = 9;  Kr = 280; Nr = 140; ld = 140; le = e;         base = 0; }
    else if (e < 82432) { W = W2; NT = 16; Kr = 140; Nr = 256; ld = 256; le = e - 41472; base = 41472; }
    else if (e < 98816) { W = Wi; NT = 2;  Kr = 512; Nr = 24;  ld = 24;  le = e - 82432; base = 82432; }
    else return;
    int i = le & 7, lane = (le >> 3) & 63, frag = le >> 9;
    int kt = frag / NT, nt = frag - kt * NT;
    int k = kt * 32 + ((lane >> 4) << 3) + i;
    int n = nt * 16 + (lane & 15);
    float v = (k < Kr && n < Nr) ? W[k * ld + n] : 0.0f;
    g_wpack[base + le] = f2bf(v);
}

// ---- main fused kernel: 256 threads = 4 waves, each wave 32 rows ----
__global__ __launch_bounds__(256, 3) void icm_main(
    const float* __restrict__ cf, const float* __restrict__ nf,
    const int* __restrict__ act,
    const float* __restrict__ b1, const float* __restrict__ b2,
    const float* __restrict__ bi,
    float* __restrict__ out)
{
    // LDS: two 11264-B staging buffers only (no h buffer).
    __shared__ char smem[22528];
    char* wstA = smem;
    char* wstB = smem + 11264;

    const int tid  = threadIdx.x;
    const int lane = tid & 63;
    const int wave = tid >> 6;
    const int lhi  = lane >> 4;   // 0..3
    const int llo  = lane & 15;   // 0..15

    const long rowbase = (long)blockIdx.x * 128 + wave * 32;
    const char* gw = (const char*)g_wpack;

    // phase-1 staging: frag f at stage byte f*1024; W1(kt,0..8)=9216B, Wi(kt,0..1)
    auto stage1 = [&](char* dst, int kt) {
        const char* w1b = gw + kt * 9216;
        const char* wib = gw + 164864 + kt * 2048;
        const int nb = (kt == 8) ? 9216 : 11264;
        #pragma unroll
        for (int k = 0; k < 3; ++k) {
            int b = k * 4096 + wave * 1024;
            if (b < nb) {
                const char* src = (b < 9216) ? (w1b + b) : (wib + (b - 9216));
                gl_lds16(src + lane * 16, dst + b);
            }
        }
    };
    // 8KB contiguous stage
    auto stage8 = [&](char* dst, const char* src) {
        #pragma unroll
        for (int k = 0; k < 2; ++k) {
            int b = k * 4096 + wave * 1024;
            gl_lds16(src + b + lane * 16, dst + b);
        }
    };

    // prologue scalars
    int i0[2], i1[2], i2[2];
    #pragma unroll
    for (int m = 0; m < 2; ++m) {
        long r = rowbase + m * 16 + llo;
        long f = r >> 6; int n = (int)(r & 63);
        i0[m] = act[(f * 3 + 0) * 64 + n];
        i1[m] = act[(f * 3 + 1) * 64 + n] + 8;
        i2[m] = act[(f * 3 + 2) * 64 + n] + 16;
    }
    float bi0 = bi[llo];
    float bi1 = (llo < 8) ? bi[16 + llo] : 0.f;

    const float4v fz = {0.f, 0.f, 0.f, 0.f};
    float4v acc1[2][9];          // h^T D-tiles: lane holds h[m*16+llo][nt*16+lhi*4+r]
    float4v acc3[2][2];
    #pragma unroll
    for (int m = 0; m < 2; ++m) {
        #pragma unroll
        for (int n = 0; n < 9; ++n) acc1[m][n] = fz;
        acc3[m][0] = fz; acc3[m][1] = fz;
    }

    const float* cfb[2];
    #pragma unroll
    for (int m = 0; m < 2; ++m)
        cfb[m] = cf + (rowbase + m * 16 + llo) * 256 + lhi * 8;

    // ================= Phase 1: GEMM1 (swapped) + GEMM3a over cf ============
    float4v pa0[2], pa1[2], pb0[2], pb1[2];
    stage1(wstA, 0);
    #pragma unroll
    for (int m = 0; m < 2; ++m) {
        pa0[m] = *(const float4v*)(cfb[m]);
        pa1[m] = *(const float4v*)(cfb[m] + 4);
        pb0[m] = *(const float4v*)(cfb[m] + 32);
        pb1[m] = *(const float4v*)(cfb[m] + 36);
    }
    __syncthreads();

    #pragma unroll 1
    for (int kt = 0; kt < 8; ++kt) {
        stage1((kt & 1) ? wstA : wstB, kt + 1);
        const char* wb = (kt & 1) ? wstB : wstA;
        short8 a[2];
        if (kt & 1) { a[0] = cvt8(pb0[0], pb1[0]); a[1] = cvt8(pb0[1], pb1[1]); }
        else        { a[0] = cvt8(pa0[0], pa1[0]); a[1] = cvt8(pa0[1], pa1[1]); }
        if (kt <= 5) {
            int o = (kt + 2) * 32;
            if (kt & 1) {
                #pragma unroll
                for (int m = 0; m < 2; ++m) {
                    pb0[m] = *(const float4v*)(cfb[m] + o);
                    pb1[m] = *(const float4v*)(cfb[m] + o + 4);
                }
            } else {
                #pragma unroll
                for (int m = 0; m < 2; ++m) {
                    pa0[m] = *(const float4v*)(cfb[m] + o);
                    pa1[m] = *(const float4v*)(cfb[m] + o + 4);
                }
            }
        }
        #pragma unroll
        for (int nt = 0; nt < 9; ++nt) {
            short8 bf = *(const short8*)(wb + (nt << 10) + (lane << 4));
            acc1[0][nt] = MFMA16(bf, a[0], acc1[0][nt], 0, 0, 0);   // SWAPPED
            acc1[1][nt] = MFMA16(bf, a[1], acc1[1][nt], 0, 0, 0);
        }
        #pragma unroll
        for (int nt = 0; nt < 2; ++nt) {
            short8 bf = *(const short8*)(wb + ((9 + nt) << 10) + (lane << 4));
            acc3[0][nt] = MFMA16(a[0], bf, acc3[0][nt], 0, 0, 0);   // normal
            acc3[1][nt] = MFMA16(a[1], bf, acc3[1][nt], 0, 0, 0);
        }
        __syncthreads();
    }
    // kt = 8: one-hot action K-tile (reads wstA, staged at kt=7)
    {
        short8 a[2];
        #pragma unroll
        for (int m = 0; m < 2; ++m) {
            #pragma unroll
            for (int i = 0; i < 8; ++i) {
                int kk = lhi * 8 + i;
                a[m][i] = (kk == i0[m] || kk == i1[m] || kk == i2[m])
                              ? (short)0x3F80 : (short)0;
            }
        }
        #pragma unroll
        for (int nt = 0; nt < 9; ++nt) {
            short8 bf = *(const short8*)(wstA + (nt << 10) + (lane << 4));
            acc1[0][nt] = MFMA16(bf, a[0], acc1[0][nt], 0, 0, 0);   // SWAPPED
            acc1[1][nt] = MFMA16(bf, a[1], acc1[1][nt], 0, 0, 0);
        }
    }
    __syncthreads();   // all reads of wstA/wstB done -> restage

    // ---- stage phase-2 weights (Wi frags 16..31) as two 8KB halves ----
    stage8(wstA, gw + 164864 + 16384);     // frags 16..23
    stage8(wstB, gw + 164864 + 24576);     // frags 24..31

    // ---- epilogue 1 (in registers): bias + leaky -> bf16 pair dwords ----
    // lane's cols: nt*16 + lhi*4 + {0..3}; pad cols (>=140) inert (W2p rows 0).
    int w01[2][9], w23[2][9];
    #pragma unroll
    for (int nt = 0; nt < 9; ++nt) {
        int bb = nt * 16 + lhi * 4; bb = bb > 136 ? 136 : bb;
        float4v b1v = *(const float4v*)(b1 + bb);
        #pragma unroll
        for (int m = 0; m < 2; ++m) {
            float v0 = acc1[m][nt][0] + b1v[0]; v0 = v0 > 0.f ? v0 : 0.1f * v0;
            float v1 = acc1[m][nt][1] + b1v[1]; v1 = v1 > 0.f ? v1 : 0.1f * v1;
            float v2 = acc1[m][nt][2] + b1v[2]; v2 = v2 > 0.f ? v2 : 0.1f * v2;
            float v3 = acc1[m][nt][3] + b1v[3]; v3 = v3 > 0.f ? v3 : 0.1f * v3;
            w01[m][nt] = pk2(v0, v1);
            w23[m][nt] = pk2(v2, v3);
        }
    }

    // nf features for kt0/kt1
    const float* nfb[2];
    #pragma unroll
    for (int m = 0; m < 2; ++m)
        nfb[m] = nf + (rowbase + m * 16 + llo) * 256 + lhi * 8;
    #pragma unroll
    for (int m = 0; m < 2; ++m) {
        pa0[m] = *(const float4v*)(nfb[m]);
        pa1[m] = *(const float4v*)(nfb[m] + 4);
        pb0[m] = *(const float4v*)(nfb[m] + 32);
        pb1[m] = *(const float4v*)(nfb[m] + 36);
    }
    __syncthreads();                       // Wi staging visible

    // ================= Phase 2: GEMM3b over nf (no barriers) ================
    #pragma unroll 1
    for (int kt = 0; kt < 8; ++kt) {
        short8 a[2];
        if (kt & 1) { a[0] = cvt8(pb0[0], pb1[0]); a[1] = cvt8(pb0[1], pb1[1]); }
        else        { a[0] = cvt8(pa0[0], pa1[0]); a[1] = cvt8(pa0[1], pa1[1]); }
        if (kt <= 5) {
            int o = (kt + 2) * 32;
            if (kt & 1) {
                #pragma unroll
                for (int m = 0; m < 2; ++m) {
                    pb0[m] = *(const float4v*)(nfb[m] + o);
                    pb1[m] = *(const float4v*)(nfb[m] + o + 4);
                }
            } else {
                #pragma unroll
                for (int m = 0; m < 2; ++m) {
                    pa0[m] = *(const float4v*)(nfb[m] + o);
                    pa1[m] = *(const float4v*)(nfb[m] + o + 4);
                }
            }
        }
        #pragma unroll
        for (int nt = 0; nt < 2; ++nt) {
            int f = 2 * kt + nt;           // Wi local frag 0..15
            const char* bse = smem + ((f & 8) ? 11264 : 0) + ((f & 7) << 10);
            short8 bf = *(const short8*)(bse + (lane << 4));
            acc3[0][nt] = MFMA16(a[0], bf, acc3[0][nt], 0, 0, 0);
            acc3[1][nt] = MFMA16(a[1], bf, acc3[1][nt], 0, 0, 0);
        }
    }
    // store action_pred (cols < 24), f32
    float* out2 = out + 67108864L;
    #pragma unroll
    for (int m = 0; m < 2; ++m) {
        #pragma unroll
        for (int nt = 0; nt < 2; ++nt) {
            int col = nt * 16 + llo;
            if (col < 24) {
                float bb = (nt == 0) ? bi0 : bi1;
                #pragma unroll
                for (int r = 0; r < 4; ++r) {
                    long row = rowbase + m * 16 + lhi * 4 + r;
                    out2[row * 24 + col] = acc3[m][nt][r] + bb;
                }
            }
        }
    }
    __syncthreads();   // all reads of Wi staging done -> restage for W2

    // ---- first W2 half-stage (p=0,kt=0 -> wstA), overlap with shuffle ----
    stage8(wstA, gw + 82944);

    // ---- in-register transpose: h^T D-layout -> GEMM2 A-frags ----
    // lane (llo,lhi) needs h cols kt*32+lhi*8+{0..7} of its row m*16+llo.
    // chunks live in llo-group lanes lhi' = 2*(lhi&1)+{0,1}, reg tile
    // nt' = 2kt + (lhi>>1)  (nt'=9 for kt=4,hi -> garbage, inert via W2p zeros).
    short8 hfrag[2][5];
    {
        int addrA = ((lane & 15) + ((lane & 16) ? 32 : 0)) * 4;
        int addrB = addrA + 64;
        bool hisel = (lane & 32) != 0;
        #pragma unroll
        for (int m = 0; m < 2; ++m) {
            #pragma unroll
            for (int kt = 0; kt < 5; ++kt) {
                const int j0 = 2 * kt;
                const int j1 = (2 * kt + 1 > 8) ? 8 : (2 * kt + 1);
                int u0 = w01[m][j0], u1 = w23[m][j0];
                int u2 = w01[m][j1], u3 = w23[m][j1];
                int a0 = __builtin_amdgcn_ds_bpermute(addrA, u0);
                int a2 = __builtin_amdgcn_ds_bpermute(addrA, u2);
                int b0 = __builtin_amdgcn_ds_bpermute(addrA, u1);
                int b2 = __builtin_amdgcn_ds_bpermute(addrA, u3);
                int c0 = __builtin_amdgcn_ds_bpermute(addrB, u0);
                int c2 = __builtin_amdgcn_ds_bpermute(addrB, u2);
                int e0 = __builtin_amdgcn_ds_bpermute(addrB, u1);
                int e2 = __builtin_amdgcn_ds_bpermute(addrB, u3);
                union { int d[4]; short8 s; } t;
                t.d[0] = hisel ? a2 : a0;
                t.d[1] = hisel ? b2 : b0;
                t.d[2] = hisel ? c2 : c0;
                t.d[3] = hisel ? e2 : e0;
                hfrag[m][kt] = t.s;
            }
        }
    }
    __syncthreads();   // W2(0,0) staging visible

    // ================= Phase 3: GEMM2, two n-halves, 8KB half-stages ========
    #pragma unroll 1
    for (int p = 0; p < 2; ++p) {
        float4v acc2[2][8];
        #pragma unroll
        for (int m = 0; m < 2; ++m)
            #pragma unroll
            for (int n = 0; n < 8; ++n) acc2[m][n] = fz;

        #pragma unroll
        for (int kt = 0; kt < 5; ++kt) {
            int q = p * 5 + kt;
            if (q < 9) {
                int qn = q + 1;
                int off = ((qn >= 5 ? qn - 5 : qn) * 16 + (qn >= 5 ? 8 : 0)) << 10;
                stage8((q & 1) ? wstA : wstB, gw + 82944 + off);  // buf(q+1)
            }
            const char* wb = (q & 1) ? wstB : wstA;
            #pragma unroll
            for (int n = 0; n < 8; ++n) {
                short8 bf = *(const short8*)(wb + (n << 10) + (lane << 4));
                acc2[0][n] = MFMA16(hfrag[0][kt], bf, acc2[0][n], 0, 0, 0);
                acc2[1][n] = MFMA16(hfrag[1][kt], bf, acc2[1][n], 0, 0, 0);
            }
            if (q < 9) __syncthreads();
        }
        // stores for this n-half
        #pragma unroll
        for (int m = 0; m < 2; ++m) {
            #pragma unroll
            for (int n = 0; n < 8; ++n) {
                int col = (p * 8 + n) * 16 + llo;
                float bb = b2[col];
                #pragma unroll
                for (int r = 0; r < 4; ++r) {
                    long row = rowbase + m * 16 + lhi * 4 + r;
                    out[row * 256 + col] = acc2[m][n][r] + bb;
                }
            }
        }
    }
}

extern "C" void kernel_launch(void* const* d_in, const int* in_sizes, int n_in,
                              void* d_out, int out_size, void* d_ws, size_t ws_size,
                              hipStream_t stream) {
    const float *cf = nullptr, *nf = nullptr, *W1 = nullptr, *b1 = nullptr;
    const float *W2 = nullptr, *b2 = nullptr, *Wi = nullptr, *bi = nullptr;
    const int *ac = nullptr;
    for (int i = 0; i < n_in; ++i) {
        int s = in_sizes[i];
        const void* p = d_in[i];
        switch (s) {
            case 67108864: if (!cf) cf = (const float*)p; else nf = (const float*)p; break;
            case 786432:   ac = (const int*)p;   break;
            case 39200:    W1 = (const float*)p; break;
            case 140:      b1 = (const float*)p; break;
            case 35840:    W2 = (const float*)p; break;
            case 256:      b2 = (const float*)p; break;
            case 12288:    Wi = (const float*)p; break;
            case 24:       bi = (const float*)p; break;
            default: break;
        }
    }
    float* ob = (float*)d_out;

    pack_weights<<<386, 256, 0, stream>>>(W1, W2, Wi);
    icm_main<<<2048, 256, 0, stream>>>(cf, nf, ac, b1, b2, bi, ob);
}